// Round 1
// baseline (203.390 us; speedup 1.0000x reference)
//
#include <hip/hip_runtime.h>
#include <math.h>

// Problem constants (match reference)
constexpr int C   = 6;
constexpr int NR  = 2048;
constexpr int NC  = 2048;
constexpr int KS  = 10;
constexpr int PAD = 4;              // top/left circular halo

// Streaming config: thread owns 4 output cols (one float4); 2 blocks in x cover a
// full 2048-col row; block streams a 16-row output strip (25 input rows w/ halo).
// No LDS, no barriers: H-pass from global (coalesced dwordx4, overlapping windows
// served by L1), V-pass in a 10-deep register ring. All row base addressing is
// wave-uniform -> SALU; per-lane col offsets are loop-invariant.
//
// R4: R 32->16. Rocprof showed latency-bound (VALUBusy 14%, hbm 31%, occ 27%):
// grid was 768 blocks = 3 blocks/CU = 3 waves/SIMD -> ~510 cyc hiding capacity
// vs ~900 cyc HBM miss latency. R=16 doubles the grid to 1536 = 6 blocks/CU
// (6 waves/SIMD, ~1020 cyc cover). Halo amp 1.28x -> 1.56x is cheap at 14% VALU.
constexpr int R    = 16;            // output rows per block
constexpr int NIT  = R + KS - 1;    // 25 streamed H-rows
constexpr int CPT  = 4;             // cols per thread
constexpr int BW   = 256 * CPT;     // 1024 cols per block

__device__ __constant__ float MTFf[C] = {0.38f, 0.34f, 0.34f, 0.26f, 0.22f, 0.23f};

__global__ __launch_bounds__(256, 6)   // 6 blocks/CU needed; VGPR cap 85 (live ~40 -> safe)
void s2_blur_ring(const float* __restrict__ x, float* __restrict__ out)
{
    const int t  = threadIdx.x;
    const int c  = blockIdx.z;
    const int r0 = blockIdx.y * R;
    const int jt = blockIdx.x * BW + t * CPT;   // first output col of this thread

    const float* xc = x   + (size_t)c * NR * NC;
    float*       oc = out + (size_t)c * NR * NC;

    // ---- per-thread fp32 weights (verified absmax 0.0039 << 0.0325) ----
    float w[KS];
    {
        float mtf    = MTFf[c];
        float sig    = 2.0f * sqrtf(-2.0f * logf(mtf) / (float)(M_PI * M_PI));
        float inv2s2 = 1.0f / (2.0f * sig * sig);
        float s = 0.0f;
        #pragma unroll
        for (int d = 0; d < KS; ++d) {
            float cd = -4.5f + (float)d;
            w[d] = expf(-cd * cd * inv2s2);
            s += w[d];
        }
        #pragma unroll
        for (int d = 0; d < KS; ++d) w[d] /= s;
    }

    // ---- per-lane wrapped float4-group offsets (loop-invariant; wrap is a
    // multiple of 4 floats so a 16B group never splits) ----
    const int off0 = (jt - PAD +  0 + NC) & (NC - 1);
    const int off1 = (jt - PAD +  4 + NC) & (NC - 1);
    const int off2 = (jt - PAD +  8 + NC) & (NC - 1);
    const int off3 = (jt - PAD + 12 + NC) & (NC - 1);

    // V-pass accumulator ring: slot m%10 holds strip-row m in flight
    float acc[KS][CPT];
    #pragma unroll
    for (int s = 0; s < KS; ++s)
        #pragma unroll
        for (int q = 0; q < CPT; ++q) acc[s][q] = 0.0f;

    // prime the pipeline: row k=0
    float4 f0, f1, f2, f3;
    {
        const float* rp = xc + (size_t)((r0 - PAD + NR) & (NR - 1)) * NC;
        f0 = *(const float4*)(rp + off0);
        f1 = *(const float4*)(rp + off1);
        f2 = *(const float4*)(rp + off2);
        f3 = *(const float4*)(rp + off3);
    }

    #pragma unroll
    for (int k = 0; k < NIT; ++k) {
        // prefetch row k+1 (loads in flight across ~85 FMAs + wave TLP)
        float4 g0, g1, g2, g3;
        if (k + 1 < NIT) {
            const float* rp = xc + (size_t)((r0 - PAD + k + 1) & (NR - 1)) * NC;
            g0 = *(const float4*)(rp + off0);
            g1 = *(const float4*)(rp + off1);
            g2 = *(const float4*)(rp + off2);
            g3 = *(const float4*)(rp + off3);
        }

        // ---- H-pass for row k: H[q] = sum_d w[d] * window[q+d] ----
        const float f[16] = {f0.x, f0.y, f0.z, f0.w,
                             f1.x, f1.y, f1.z, f1.w,
                             f2.x, f2.y, f2.z, f2.w,
                             f3.x, f3.y, f3.z, f3.w};
        float H[CPT];
        #pragma unroll
        for (int q = 0; q < CPT; ++q) {
            float a = 0.0f;
            #pragma unroll
            for (int d = 0; d < KS; ++d) a = fmaf(w[d], f[q + d], a);
            H[q] = a;
        }

        // ---- V-pass ring update: H row k feeds strip rows m = k-o, weight w[o] ----
        #pragma unroll
        for (int o = 0; o < KS; ++o) {
            const int m = k - o;
            if (m >= 0 && m < R) {
                const int s = m % KS;
                #pragma unroll
                for (int q = 0; q < CPT; ++q)
                    acc[s][q] = fmaf(w[o], H[q], acc[s][q]);
            }
        }

        // ---- emit finished strip row m = k-9 ----
        if (k >= KS - 1) {
            const int m = k - (KS - 1);
            const int s = m % KS;
            float* orow = oc + (size_t)(r0 + m) * NC;   // wave-uniform base
            *(float4*)(orow + jt) = make_float4(acc[s][0], acc[s][1], acc[s][2], acc[s][3]);
            #pragma unroll
            for (int q = 0; q < CPT; ++q) acc[s][q] = 0.0f;
        }

        f0 = g0; f1 = g1; f2 = g2; f3 = g3;
    }
}

extern "C" void kernel_launch(void* const* d_in, const int* in_sizes, int n_in,
                              void* d_out, int out_size, void* d_ws, size_t ws_size,
                              hipStream_t stream) {
    const float* x = (const float*)d_in[0];
    float* out = (float*)d_out;
    dim3 grid(NC / BW, NR / R, C);   // 2 x 128 x 6 = 1536 blocks = 6 blocks/CU exactly
    dim3 block(256);
    s2_blur_ring<<<grid, block, 0, stream>>>(x, out);
}

// Round 4
// 184.517 us; speedup vs baseline: 1.1023x; 1.1023x over previous
//
#include <hip/hip_runtime.h>
#include <math.h>

// Problem constants (match reference)
constexpr int C   = 6;
constexpr int NR  = 2048;
constexpr int NC  = 2048;
constexpr int KS  = 10;
constexpr int PAD = 4;              // top/left circular halo

// R7: LDS-staged streaming, exec-safe staging.
// R2/R4 rocprof: effective BW pinned at 2.55 TB/s across 12 AND 24 waves/CU
// (VALUBusy 14%) -> per-CU request-queue limit fed by 4x-redundant overlapping
// float4 window loads. Fix: wave stages its 272-float row segment into a
// wave-private LDS ring via global_load_lds, H-pass reads windows from LDS.
// R6 failed absmax 2.2: suspected LDS-DMA under divergent exec (if(ln<4) tail
// load) writing ALL lanes' slots -> corrupts neighbor ring slots. R7: both
// staging loads are FULL-WAVE. Load B is shifted by 16 floats: lanes 0..59
// rewrite floats [16,256) with byte-identical data (idempotent), lanes 60..63
// write the halo [256,272). No exec masks, no barriers (wave-private bufs);
// pipelining via counted s_waitcnt vmcnt(N), depth-3 prefetch, steady vmcnt(6)
// (only loads counted -> extra outstanding stores just add conservatism).
constexpr int R     = 32;           // output rows per block
constexpr int NIT   = R + KS - 1;   // 41 streamed H-rows
constexpr int CPT   = 4;            // cols per thread
constexpr int BW    = 256 * CPT;    // 1024 cols per block
constexpr int DEPTH = 4;            // LDS row-ring buffers per wave (3 in flight)
constexpr int WROW  = 272;          // floats per wave row buffer (268 used, 16B mult)

__device__ __constant__ float MTFf[C] = {0.38f, 0.34f, 0.34f, 0.26f, 0.22f, 0.23f};

template<int K> struct IC { static constexpr int v = K; };
template<int K, int N, typename F>
__device__ __forceinline__ void static_for(F&& f) {
    if constexpr (K < N) { f(IC<K>{}); static_for<K + 1, N>(f); }
}

template<int N> __device__ __forceinline__ void vm_wait() {
    asm volatile("s_waitcnt vmcnt(%0)" :: "n"(N) : "memory");
}

__global__ __launch_bounds__(256, 3)   // 3 blocks/CU (grid 768)
void s2_blur_lds(const float* __restrict__ x, float* __restrict__ out)
{
    __shared__ __align__(16) float lds[4][DEPTH][WROW];   // [wave][ring][row seg] 17.4 KB

    const int t     = threadIdx.x;
    const int ln    = t & 63;
    const int wv    = t >> 6;
    const int c     = blockIdx.z;
    const int r0    = blockIdx.y * R;
    const int jt    = blockIdx.x * BW + t * CPT;     // first output col of this thread
    const int wbase = blockIdx.x * BW + wv * 256;    // wave's col-chunk start

    const float* xc = x   + (size_t)c * NR * NC;
    float*       oc = out + (size_t)c * NR * NC;

    // ---- per-thread fp32 weights (verified absmax 0.0039 << 0.0325) ----
    float w[KS];
    {
        float mtf    = MTFf[c];
        float sig    = 2.0f * sqrtf(-2.0f * logf(mtf) / (float)(M_PI * M_PI));
        float inv2s2 = 1.0f / (2.0f * sig * sig);
        float s = 0.0f;
        #pragma unroll
        for (int d = 0; d < KS; ++d) {
            float cd = -4.5f + (float)d;
            w[d] = expf(-cd * cd * inv2s2);
            s += w[d];
        }
        #pragma unroll
        for (int d = 0; d < KS; ++d) w[d] /= s;
    }

    // ---- staging source cols (circular; every 16B group is 4-float aligned so
    // it never straddles the wrap). LDS float i of a slot <- col wbase-4+i.
    // Load A: lane ln -> floats [4ln, 4ln+4)      <- cols wbase-4+4ln..
    // Load B: lane ln -> floats [16+4ln, 16+4ln+4) <- cols wbase+12+4ln..
    //   (lanes 0..59 duplicate load A's data byte-identically -> idempotent;
    //    lanes 60..63 supply the halo floats [256,272)) ----
    const int sA = (wbase -  4 + ln * 4 + NC) & (NC - 1);
    const int sB = (wbase + 12 + ln * 4 + NC) & (NC - 1);

    float* lb0 = &lds[wv][0][0];

    auto issue = [&](int k) {   // fetch input strip-row k -> ring slot k&3 (2 full-wave DMAs)
        const float* rp = xc + (size_t)((r0 - PAD + k + NR) & (NR - 1)) * NC;
        float* lb = lb0 + (k & (DEPTH - 1)) * WROW;
        __builtin_amdgcn_global_load_lds(
            (const __attribute__((address_space(1))) void*)(rp + sA),
            (__attribute__((address_space(3))) void*)(lb), 16, 0, 0);
        __builtin_amdgcn_global_load_lds(
            (const __attribute__((address_space(1))) void*)(rp + sB),
            (__attribute__((address_space(3))) void*)(lb + 16), 16, 0, 0);
    };

    // V-pass accumulator ring: slot m%10 holds strip-row m in flight
    float acc[KS][CPT] = {};

    // prime: rows 0..2 in flight (6 vmcnt ops)
    issue(0); issue(1); issue(2);

    static_for<0, NIT>([&](auto ic) {
        constexpr int k = decltype(ic)::v;

        // keep 3 rows ahead in flight
        if constexpr (k + 3 < NIT) issue(k + 3);

        // wait for row k's 2 loads: newer loads = 2 * (#rows in flight beyond k).
        // Stores are NOT counted in this formula -> outstanding stores only make
        // the wait MORE conservative (cannot under-wait). Steady state: vmcnt(6).
        constexpr int rem = NIT - 1 - k;
        vm_wait<2 * (rem < 3 ? rem : 3)>();

        // ---- H-pass from LDS: thread t window = floats [4*ln, 4*ln+16) of wave seg ----
        const float* lb = lb0 + (k & (DEPTH - 1)) * WROW + ln * 4;
        float4 a0 = *(const float4*)(lb + 0);
        float4 a1 = *(const float4*)(lb + 4);
        float4 a2 = *(const float4*)(lb + 8);
        float4 a3 = *(const float4*)(lb + 12);
        const float f[16] = {a0.x, a0.y, a0.z, a0.w,
                             a1.x, a1.y, a1.z, a1.w,
                             a2.x, a2.y, a2.z, a2.w,
                             a3.x, a3.y, a3.z, a3.w};
        float H[CPT];
        #pragma unroll
        for (int q = 0; q < CPT; ++q) {
            float a = 0.0f;
            #pragma unroll
            for (int d = 0; d < KS; ++d) a = fmaf(w[d], f[q + d], a);
            H[q] = a;
        }

        // ---- V-pass ring update: H row k feeds strip rows m = k-o, weight w[o] ----
        #pragma unroll
        for (int o = 0; o < KS; ++o) {
            const int m = k - o;
            if (m >= 0 && m < R) {
                const int s = m % KS;
                #pragma unroll
                for (int q = 0; q < CPT; ++q)
                    acc[s][q] = fmaf(w[o], H[q], acc[s][q]);
            }
        }

        // ---- emit finished strip row m = k-9 ----
        if constexpr (k >= KS - 1) {
            constexpr int m = k - (KS - 1);
            constexpr int s = m % KS;
            float* orow = oc + (size_t)(r0 + m) * NC;   // wave-uniform base
            *(float4*)(orow + jt) = make_float4(acc[s][0], acc[s][1], acc[s][2], acc[s][3]);
            #pragma unroll
            for (int q = 0; q < CPT; ++q) acc[s][q] = 0.0f;
        }
    });
}

extern "C" void kernel_launch(void* const* d_in, const int* in_sizes, int n_in,
                              void* d_out, int out_size, void* d_ws, size_t ws_size,
                              hipStream_t stream) {
    const float* x = (const float*)d_in[0];
    float* out = (float*)d_out;
    dim3 grid(NC / BW, NR / R, C);   // 2 x 64 x 6 = 768 blocks = 3 blocks/CU
    dim3 block(256);
    s2_blur_lds<<<grid, block, 0, stream>>>(x, out);
}